// Round 5
// baseline (915.961 us; speedup 1.0000x reference)
//
#include <hip/hip_runtime.h>
#include <hip/hip_bf16.h>
#include <math.h>

// ---------------------------------------------------------------------------
// Qwen3 attention block: T=4096, HIDDEN=2048, 16 Q heads, 8 KV heads,
// HEAD_DIM=128, rope theta 1e6, rms eps 1e-6, causal.
// fp32 in/out; bf16 internally for MFMA with fp32 accumulation.
//
// ws layout (84 MB, regions reused across phases):
//   qkv  bf16 [4096][4096]  @ 0
//   qn   bf16 [4096][2048]  @ 16777216   (also wo after attn)
//   kn   bf16 [4096][1024]  @ 25165824   (kn+vt region doubles as wq pre-gemm1)
//   vt   bf16 [1024][4096]  @ 29360128
//   ao   bf16 [4096][2048]  @ 33554432   (doubles as hb pre-attn)
// ---------------------------------------------------------------------------

typedef __bf16 bf16;
typedef __bf16 bf16x4 __attribute__((ext_vector_type(4)));
typedef __bf16 bf16x8 __attribute__((ext_vector_type(8)));
typedef float  f32x4  __attribute__((ext_vector_type(4)));

__device__ __forceinline__ f32x4 mfma16(bf16x8 a, bf16x8 b, f32x4 c) {
  return __builtin_amdgcn_mfma_f32_16x16x32_bf16(a, b, c, 0, 0, 0);
}

// 16x16x16 bf16 MFMA via inline asm (ISA §10: A 2 regs, B 2 regs, C/D 4).
// A/B frag: [m or n = l16][k = quad*4 + j] -- matches S^T C-layout directly.
// s_nop 2 guards the VALU-write -> MFMA-read RAW hazard (inline asm bypasses
// the compiler's hazard recognizer).
__device__ __forceinline__ void mfma16x16(const bf16x4& a, const bf16x4& b,
                                          f32x4& c) {
  asm volatile("s_nop 2\n\tv_mfma_f32_16x16x16_bf16 %0, %1, %2, %0"
               : "+v"(c)
               : "v"(a), "v"(b));
}

__device__ __forceinline__ void load8_to_lds(const float* src, bf16* dst) {
  float4 a = *reinterpret_cast<const float4*>(src);
  float4 b = *reinterpret_cast<const float4*>(src + 4);
  bf16x8 v = {(bf16)a.x, (bf16)a.y, (bf16)a.z, (bf16)a.w,
              (bf16)b.x, (bf16)b.y, (bf16)b.z, (bf16)b.w};
  *reinterpret_cast<bf16x8*>(dst) = v;
}
__device__ __forceinline__ void load8_to_lds(const bf16* src, bf16* dst) {
  *reinterpret_cast<uint4*>(dst) = *reinterpret_cast<const uint4*>(src);
}
__device__ __forceinline__ void store_c(float* p, float v) { *p = v; }
__device__ __forceinline__ void store_c(bf16* p, float v) { *p = (bf16)v; }

// ---------------------------------------------------------------------------
// fp32 -> bf16 cast, 8 elems/thread
// ---------------------------------------------------------------------------
__global__ __launch_bounds__(256) void cast_bf16(const float* __restrict__ s,
                                                 bf16* __restrict__ d) {
  int i = blockIdx.x * 256 + threadIdx.x;
  float4 a = reinterpret_cast<const float4*>(s)[i * 2];
  float4 b = reinterpret_cast<const float4*>(s)[i * 2 + 1];
  bf16x8 v = {(bf16)a.x, (bf16)a.y, (bf16)a.z, (bf16)a.w,
              (bf16)b.x, (bf16)b.y, (bf16)b.z, (bf16)b.w};
  reinterpret_cast<bf16x8*>(d)[i] = v;
}

// ---------------------------------------------------------------------------
// C[M][N] = A[M][K] @ B[N][K]^T   (fp32 accumulate) — unchanged
// ---------------------------------------------------------------------------
template <typename TA, typename TB, typename TC>
__global__ __launch_bounds__(256) void gemm_bt(const TA* __restrict__ A,
                                               const TB* __restrict__ B,
                                               TC* __restrict__ C,
                                               int M, int N, int K) {
  __shared__ __align__(16) bf16 As[128 * 40];
  __shared__ __align__(16) bf16 Bs[128 * 40];

  const int tid  = threadIdx.x;
  const int wave = tid >> 6, lane = tid & 63;
  const int quad = lane >> 4, l16 = lane & 15;
  const int wm = (wave >> 1) * 64, wn = (wave & 1) * 64;
  const int n0 = blockIdx.x * 128, m0 = blockIdx.y * 128;

  const f32x4 zero = {0.f, 0.f, 0.f, 0.f};
  f32x4 acc[4][4];
#pragma unroll
  for (int i = 0; i < 4; ++i)
#pragma unroll
    for (int j = 0; j < 4; ++j) acc[i][j] = zero;

  for (int k0 = 0; k0 < K; k0 += 32) {
#pragma unroll
    for (int it = 0; it < 2; ++it) {
      int linear = it * 2048 + tid * 8;
      int r = linear >> 5, c = linear & 31;
      load8_to_lds(&A[(size_t)(m0 + r) * K + k0 + c], &As[r * 40 + c]);
      load8_to_lds(&B[(size_t)(n0 + r) * K + k0 + c], &Bs[r * 40 + c]);
    }
    __syncthreads();

    bf16x8 af[4], bfr[4];
#pragma unroll
    for (int i = 0; i < 4; ++i)
      af[i] = *reinterpret_cast<const bf16x8*>(&As[(wm + i * 16 + l16) * 40 + quad * 8]);
#pragma unroll
    for (int j = 0; j < 4; ++j)
      bfr[j] = *reinterpret_cast<const bf16x8*>(&Bs[(wn + j * 16 + l16) * 40 + quad * 8]);
#pragma unroll
    for (int i = 0; i < 4; ++i)
#pragma unroll
      for (int j = 0; j < 4; ++j)
        acc[i][j] = mfma16(af[i], bfr[j], acc[i][j]);
    __syncthreads();
  }

#pragma unroll
  for (int i = 0; i < 4; ++i)
#pragma unroll
    for (int j = 0; j < 4; ++j)
#pragma unroll
      for (int r = 0; r < 4; ++r) {
        int row = m0 + wm + i * 16 + quad * 4 + r;
        int col = n0 + wn + j * 16 + l16;
        store_c(&C[(size_t)row * N + col], acc[i][j][r]);
      }
}

// ---------------------------------------------------------------------------
// Per-(token, head) RMS norm + rope — unchanged
// ---------------------------------------------------------------------------
__global__ __launch_bounds__(128) void norm_rope(const bf16* __restrict__ qkv,
                                                 const float* __restrict__ qw,
                                                 const float* __restrict__ kw,
                                                 const int* __restrict__ pos,
                                                 bf16* __restrict__ qn,
                                                 bf16* __restrict__ kn) {
  const int t   = blockIdx.x;
  const int hr  = blockIdx.y;
  const int tid = threadIdx.x;
  const bool isq = hr < 16;
  const int col  = isq ? hr * 128 : 2048 + (hr - 16) * 128;

  float x = (float)qkv[(size_t)t * 4096 + col + tid];
  float ss = x * x;
#pragma unroll
  for (int o = 32; o >= 1; o >>= 1) ss += __shfl_xor(ss, o);
  __shared__ float part[2];
  __shared__ float sh[128];
  if ((tid & 63) == 0) part[tid >> 6] = ss;
  __syncthreads();
  float total = part[0] + part[1];
  float rms = rsqrtf(total * (1.0f / 128.0f) + 1e-6f);
  const float* w = isq ? qw : kw;
  float xn = x * rms * w[tid];
  sh[tid] = xn;
  __syncthreads();

  int d = tid & 63;
  float inv = exp2f((float)d * (-19.93156856932417f / 64.0f));
  float fr = (float)pos[t] * inv;
  float sn, cs;
  sincosf(fr, &sn, &cs);
  float out = (tid < 64) ? (sh[tid] * cs - sh[tid + 64] * sn)
                         : (sh[tid] * cs + sh[tid - 64] * sn);
  if (isq) qn[(size_t)t * 2048 + hr * 128 + tid] = (bf16)out;
  else     kn[(size_t)t * 1024 + (hr - 16) * 128 + tid] = (bf16)out;
}

// ---------------------------------------------------------------------------
// One-time V transpose — unchanged
// ---------------------------------------------------------------------------
__global__ __launch_bounds__(256) void transpose_v(const bf16* __restrict__ qkv,
                                                   bf16* __restrict__ vt) {
  __shared__ __align__(16) bf16 tile[128 * 72];
  const int t0 = blockIdx.x * 64, kvh = blockIdx.y;
  const int tid = threadIdx.x;
#pragma unroll
  for (int it = 0; it < 2; ++it) {
    int linear = it * 4096 + tid * 16;
    int r = linear >> 7, c = linear & 127;
    union { uint4 v; bf16 e[8]; } u0, u1;
    u0.v = *reinterpret_cast<const uint4*>(
        &qkv[(size_t)(t0 + r) * 4096 + 3072 + kvh * 128 + c]);
    u1.v = *reinterpret_cast<const uint4*>(
        &qkv[(size_t)(t0 + r) * 4096 + 3072 + kvh * 128 + c + 8]);
#pragma unroll
    for (int j = 0; j < 8; ++j) tile[(c + j) * 72 + r] = u0.e[j];
#pragma unroll
    for (int j = 0; j < 8; ++j) tile[(c + 8 + j) * 72 + r] = u1.e[j];
  }
  __syncthreads();
#pragma unroll
  for (int it = 0; it < 4; ++it) {
    int linear = it * 2048 + tid * 8;
    int d = linear >> 6, c = linear & 63;
    uint4 v = *reinterpret_cast<const uint4*>(&tile[d * 72 + c]);
    *reinterpret_cast<uint4*>(&vt[(size_t)(kvh * 128 + d) * 4096 + t0 + c]) = v;
  }
}

// ---------------------------------------------------------------------------
// Flash attention v4. grid (64 swizzled q-tiles, 16 heads), block 256,
// SINGLE head per block (4 blocks/CU: LDS 35.8 KB, VGPR<=128).
// Wave w owns q rows q0+w*16..+15. S^T = K.Q^T via 16x16x32; P stays in
// registers (S^T C-layout == 16x16x16 A/B frag layout) and feeds
// O^T += V^T.P via v_mfma_f32_16x16x16_bf16 -- no P LDS round-trip.
// ---------------------------------------------------------------------------
__global__ __launch_bounds__(256, 4) void attn(const bf16* __restrict__ q,
                                               const bf16* __restrict__ k,
                                               const bf16* __restrict__ vt,
                                               bf16* __restrict__ out) {
  __shared__ __align__(16) bf16 Ks[64 * 136];  // [kv row][dim]
  __shared__ __align__(16) bf16 Vs[128 * 72];  // [dim][kv row]

  const int head = blockIdx.y, kvh = head >> 1;
  const int bx = blockIdx.x;
  // long/short pairing that survives round-robin XCD dispatch (stride 8)
  const int p  = bx >> 1;
  const int qt = (((bx & 1) ^ ((p >> 2) & 1)) == 0) ? (63 - p) : p;
  const int q0 = qt * 64;
  const int kend = q0 + 64;

  const int tid = threadIdx.x;
  const int wave = tid >> 6, lane = tid & 63;
  const int quad = lane >> 4, l16 = lane & 15;
  const int qrow = q0 + wave * 16 + l16;
  const float cExp = 0.08838834764831845f * 1.4426950408889634f; // scale*log2e

  // Q fragments: B[n=l16][k=s*32+quad*8+j]
  bf16x8 qf[4];
#pragma unroll
  for (int s = 0; s < 4; ++s)
    qf[s] = *reinterpret_cast<const bf16x8*>(
        &q[(size_t)qrow * 2048 + head * 128 + s * 32 + quad * 8]);

  const f32x4 zero = {0.f, 0.f, 0.f, 0.f};
  f32x4 o_acc[8];  // O^T: d = dt*16+quad*4+r, q = l16
#pragma unroll
  for (int dt = 0; dt < 8; ++dt) o_acc[dt] = zero;
  float m_i = -3.0e38f, l_i = 0.f;

  // ---- prefetch tile 0 into registers ----
  uint4 pk[4], pv[4];
#pragma unroll
  for (int it = 0; it < 4; ++it) {
    int linear = it * 2048 + tid * 8;
    int r = linear >> 7, c = linear & 127;
    pk[it] = *reinterpret_cast<const uint4*>(&k[(size_t)r * 1024 + kvh * 128 + c]);
    int d = linear >> 6, c2 = linear & 63;
    pv[it] = *reinterpret_cast<const uint4*>(&vt[(size_t)(kvh * 128 + d) * 4096 + c2]);
  }

  for (int k0 = 0; k0 < kend; k0 += 64) {
    // ---- publish prefetched tile to LDS ----
#pragma unroll
    for (int it = 0; it < 4; ++it) {
      int linear = it * 2048 + tid * 8;
      int r = linear >> 7, c = linear & 127;
      *reinterpret_cast<uint4*>(&Ks[r * 136 + c]) = pk[it];
      int d = linear >> 6, c2 = linear & 63;
      *reinterpret_cast<uint4*>(&Vs[d * 72 + c2]) = pv[it];
    }
    __syncthreads();

    // ---- prefetch next tile ----
    if (k0 + 64 < kend) {
      int kn0 = k0 + 64;
#pragma unroll
      for (int it = 0; it < 4; ++it) {
        int linear = it * 2048 + tid * 8;
        int r = linear >> 7, c = linear & 127;
        pk[it] = *reinterpret_cast<const uint4*>(
            &k[(size_t)(kn0 + r) * 1024 + kvh * 128 + c]);
        int d = linear >> 6, c2 = linear & 63;
        pv[it] = *reinterpret_cast<const uint4*>(
            &vt[(size_t)(kvh * 128 + d) * 4096 + kn0 + c2]);
      }
    }

    // ---- S^T = K Q^T : rows t (4 tiles of 16), cols q (16) ----
    f32x4 s_acc[4];
#pragma unroll
    for (int mt = 0; mt < 4; ++mt) {
      bf16x8 kf[4];
#pragma unroll
      for (int ks = 0; ks < 4; ++ks)
        kf[ks] = *reinterpret_cast<const bf16x8*>(
            &Ks[(mt * 16 + l16) * 136 + ks * 32 + quad * 8]);
      f32x4 sa = zero;
#pragma unroll
      for (int ks = 0; ks < 4; ++ks) sa = mfma16(kf[ks], qf[ks], sa);
      s_acc[mt] = sa;
    }

    // ---- causal mask (diagonal tile only): t > q -> -inf ----
    if (k0 == q0) {
      int tq = wave * 16 + l16;
#pragma unroll
      for (int mt = 0; mt < 4; ++mt)
#pragma unroll
        for (int r = 0; r < 4; ++r) {
          int tk = mt * 16 + quad * 4 + r;
          if (tk > tq) s_acc[mt][r] = -3.0e38f;
        }
    }

    // ---- online softmax: q fixed per lane (l16); reduce regs + quads ----
    {
      float mx = -3.0e38f;
#pragma unroll
      for (int mt = 0; mt < 4; ++mt)
#pragma unroll
        for (int r = 0; r < 4; ++r) mx = fmaxf(mx, s_acc[mt][r]);
      mx = fmaxf(mx, __shfl_xor(mx, 16));
      mx = fmaxf(mx, __shfl_xor(mx, 32));
      float mn = fmaxf(m_i, mx);
      float al = exp2f((m_i - mn) * cExp);
      m_i = mn;
      float nmc = -mn * cExp;
      float rs = 0.f;
#pragma unroll
      for (int mt = 0; mt < 4; ++mt)
#pragma unroll
        for (int r = 0; r < 4; ++r) {
          float pe = exp2f(fmaf(s_acc[mt][r], cExp, nmc));
          s_acc[mt][r] = pe;
          rs += pe;
        }
      rs += __shfl_xor(rs, 16);
      rs += __shfl_xor(rs, 32);
      l_i = l_i * al + rs;
#pragma unroll
      for (int dt = 0; dt < 8; ++dt)
#pragma unroll
        for (int r = 0; r < 4; ++r) o_acc[dt][r] *= al;
    }

    // ---- pack P in-register: B[k=t=quad*4+j][n=q=l16] per mt ----
    bf16x4 pb[4];
#pragma unroll
    for (int mt = 0; mt < 4; ++mt) {
      bf16x4 t;
#pragma unroll
      for (int r = 0; r < 4; ++r) t[r] = (bf16)s_acc[mt][r];
      pb[mt] = t;
    }

    // ---- O^T += V^T P via 16x16x16 (K=16 per mt tile) ----
#pragma unroll
    for (int dt = 0; dt < 8; ++dt) {
      f32x4 acc = o_acc[dt];
#pragma unroll
      for (int mt = 0; mt < 4; ++mt) {
        bf16x4 va = *reinterpret_cast<const bf16x4*>(
            &Vs[(dt * 16 + l16) * 72 + mt * 16 + quad * 4]);
        mfma16x16(va, pb[mt], acc);
      }
      o_acc[dt] = acc;
    }
    __syncthreads();  // all waves done with Ks/Vs before next publish
  }

  // ---- epilogue: O = O^T/l, 4 contiguous d per reg-quad ----
  float rl = __builtin_amdgcn_rcpf(l_i);
#pragma unroll
  for (int dt = 0; dt < 8; ++dt) {
    bf16x4 ov;
#pragma unroll
    for (int r = 0; r < 4; ++r) ov[r] = (bf16)(o_acc[dt][r] * rl);
    *reinterpret_cast<bf16x4*>(
        &out[(size_t)qrow * 2048 + head * 128 + dt * 16 + quad * 4]) = ov;
  }
}

// ---------------------------------------------------------------------------
extern "C" void kernel_launch(void* const* d_in, const int* in_sizes, int n_in,
                              void* d_out, int out_size, void* d_ws, size_t ws_size,
                              hipStream_t stream) {
  const float* hidden = (const float*)d_in[0];
  const float* qkv_w  = (const float*)d_in[1];
  const float* qnw    = (const float*)d_in[2];
  const float* knw    = (const float*)d_in[3];
  const float* o_w    = (const float*)d_in[4];
  const int*   pos    = (const int*)d_in[5];

  bf16* qkv = (bf16*)d_ws;                       // 4096*4096
  bf16* qn  = qkv + (size_t)4096 * 4096;         // 4096*2048
  bf16* kn  = qn  + (size_t)4096 * 2048;         // 4096*1024
  bf16* vt  = kn  + (size_t)4096 * 1024;         // 1024*4096
  bf16* ao  = vt  + (size_t)1024 * 4096;         // 4096*2048
  bf16* hb  = ao;   // bf16 hidden, dead before attn writes ao
  bf16* wq  = kn;   // bf16 qkv_w, dead before norm_rope/transpose write kn/vt
  bf16* wo  = qn;   // bf16 o_w, cast after attn (qn dead)
  float* out = (float*)d_out;

  cast_bf16<<<4096, 256, 0, stream>>>(hidden, hb);
  cast_bf16<<<4096, 256, 0, stream>>>(qkv_w, wq);
  gemm_bt<<<dim3(32, 32), 256, 0, stream>>>(hb, wq, qkv, 4096, 4096, 2048);
  norm_rope<<<dim3(4096, 24), 128, 0, stream>>>(qkv, qnw, knw, pos, qn, kn);
  transpose_v<<<dim3(64, 8), 256, 0, stream>>>(qkv, vt);
  attn<<<dim3(64, 16), 256, 0, stream>>>(qn, kn, vt, ao);
  cast_bf16<<<2048, 256, 0, stream>>>(o_w, wo);
  gemm_bt<<<dim3(16, 32), 256, 0, stream>>>(ao, wo, out, 4096, 2048, 2048);
}

// Round 6
// 699.009 us; speedup vs baseline: 1.3104x; 1.3104x over previous
//
#include <hip/hip_runtime.h>
#include <hip/hip_bf16.h>
#include <math.h>

// ---------------------------------------------------------------------------
// Qwen3 attention block: T=4096, HIDDEN=2048, 16 Q heads, 8 KV heads,
// HEAD_DIM=128, rope theta 1e6, rms eps 1e-6, causal.
// fp32 in/out; bf16 internally for MFMA with fp32 accumulation.
//
// ws layout (84 MB, regions reused across phases):
//   qkv  bf16 [4096][4096]  @ 0
//   qn   bf16 [4096][2048]  (also wo after attn)
//   kn   bf16 [4096][1024]  (kn+vt region doubles as wq pre-gemm1)
//   vt   bf16 [1024][4096]
//   ao   bf16 [4096][2048]  (doubles as hb pre-attn)
// ---------------------------------------------------------------------------

typedef __bf16 bf16;
typedef __bf16 bf16x4 __attribute__((ext_vector_type(4)));
typedef __bf16 bf16x8 __attribute__((ext_vector_type(8)));
typedef float  f32x4  __attribute__((ext_vector_type(4)));

__device__ __forceinline__ f32x4 mfma16(bf16x8 a, bf16x8 b, f32x4 c) {
  return __builtin_amdgcn_mfma_f32_16x16x32_bf16(a, b, c, 0, 0, 0);
}

// 4 chained 16x16x16 bf16 MFMAs accumulating into one C/D quad.
// A/B frag [m|n = l16][k = quad*4 + j] == S^T C-layout, so P feeds PV directly
// from registers. Single leading s_nop 2 covers the VALU-write -> MFMA-read
// hazard (same-acc MFMA->MFMA chains are HW-interlocked; compiler emits them
// back-to-back in normal GEMM code).
__device__ __forceinline__ void mfma16x16_chain4(const bf16x4& a0, const bf16x4& a1,
                                                 const bf16x4& a2, const bf16x4& a3,
                                                 const bf16x4& b0, const bf16x4& b1,
                                                 const bf16x4& b2, const bf16x4& b3,
                                                 f32x4& c) {
  asm volatile(
      "s_nop 2\n\t"
      "v_mfma_f32_16x16x16_bf16 %0, %1, %5, %0\n\t"
      "v_mfma_f32_16x16x16_bf16 %0, %2, %6, %0\n\t"
      "v_mfma_f32_16x16x16_bf16 %0, %3, %7, %0\n\t"
      "v_mfma_f32_16x16x16_bf16 %0, %4, %8, %0"
      : "+v"(c)
      : "v"(a0), "v"(a1), "v"(a2), "v"(a3),
        "v"(b0), "v"(b1), "v"(b2), "v"(b3));
}

__device__ __forceinline__ void load8_to_lds(const float* src, bf16* dst) {
  float4 a = *reinterpret_cast<const float4*>(src);
  float4 b = *reinterpret_cast<const float4*>(src + 4);
  bf16x8 v = {(bf16)a.x, (bf16)a.y, (bf16)a.z, (bf16)a.w,
              (bf16)b.x, (bf16)b.y, (bf16)b.z, (bf16)b.w};
  *reinterpret_cast<bf16x8*>(dst) = v;
}
__device__ __forceinline__ void load8_to_lds(const bf16* src, bf16* dst) {
  *reinterpret_cast<uint4*>(dst) = *reinterpret_cast<const uint4*>(src);
}
__device__ __forceinline__ void store_c(float* p, float v) { *p = v; }
__device__ __forceinline__ void store_c(bf16* p, float v) { *p = (bf16)v; }

// ---------------------------------------------------------------------------
// fp32 -> bf16 cast, 8 elems/thread
// ---------------------------------------------------------------------------
__global__ __launch_bounds__(256) void cast_bf16(const float* __restrict__ s,
                                                 bf16* __restrict__ d) {
  int i = blockIdx.x * 256 + threadIdx.x;
  float4 a = reinterpret_cast<const float4*>(s)[i * 2];
  float4 b = reinterpret_cast<const float4*>(s)[i * 2 + 1];
  bf16x8 v = {(bf16)a.x, (bf16)a.y, (bf16)a.z, (bf16)a.w,
              (bf16)b.x, (bf16)b.y, (bf16)b.z, (bf16)b.w};
  reinterpret_cast<bf16x8*>(d)[i] = v;
}

// ---------------------------------------------------------------------------
// C[M][N] = A[M][K] @ B[N][K]^T   (fp32 accumulate) — unchanged
// ---------------------------------------------------------------------------
template <typename TA, typename TB, typename TC>
__global__ __launch_bounds__(256) void gemm_bt(const TA* __restrict__ A,
                                               const TB* __restrict__ B,
                                               TC* __restrict__ C,
                                               int M, int N, int K) {
  __shared__ __align__(16) bf16 As[128 * 40];
  __shared__ __align__(16) bf16 Bs[128 * 40];

  const int tid  = threadIdx.x;
  const int wave = tid >> 6, lane = tid & 63;
  const int quad = lane >> 4, l16 = lane & 15;
  const int wm = (wave >> 1) * 64, wn = (wave & 1) * 64;
  const int n0 = blockIdx.x * 128, m0 = blockIdx.y * 128;

  const f32x4 zero = {0.f, 0.f, 0.f, 0.f};
  f32x4 acc[4][4];
#pragma unroll
  for (int i = 0; i < 4; ++i)
#pragma unroll
    for (int j = 0; j < 4; ++j) acc[i][j] = zero;

  for (int k0 = 0; k0 < K; k0 += 32) {
#pragma unroll
    for (int it = 0; it < 2; ++it) {
      int linear = it * 2048 + tid * 8;
      int r = linear >> 5, c = linear & 31;
      load8_to_lds(&A[(size_t)(m0 + r) * K + k0 + c], &As[r * 40 + c]);
      load8_to_lds(&B[(size_t)(n0 + r) * K + k0 + c], &Bs[r * 40 + c]);
    }
    __syncthreads();

    bf16x8 af[4], bfr[4];
#pragma unroll
    for (int i = 0; i < 4; ++i)
      af[i] = *reinterpret_cast<const bf16x8*>(&As[(wm + i * 16 + l16) * 40 + quad * 8]);
#pragma unroll
    for (int j = 0; j < 4; ++j)
      bfr[j] = *reinterpret_cast<const bf16x8*>(&Bs[(wn + j * 16 + l16) * 40 + quad * 8]);
#pragma unroll
    for (int i = 0; i < 4; ++i)
#pragma unroll
      for (int j = 0; j < 4; ++j)
        acc[i][j] = mfma16(af[i], bfr[j], acc[i][j]);
    __syncthreads();
  }

#pragma unroll
  for (int i = 0; i < 4; ++i)
#pragma unroll
    for (int j = 0; j < 4; ++j)
#pragma unroll
      for (int r = 0; r < 4; ++r) {
        int row = m0 + wm + i * 16 + quad * 4 + r;
        int col = n0 + wn + j * 16 + l16;
        store_c(&C[(size_t)row * N + col], acc[i][j][r]);
      }
}

// ---------------------------------------------------------------------------
// Per-(token, head) RMS norm + rope — unchanged
// ---------------------------------------------------------------------------
__global__ __launch_bounds__(128) void norm_rope(const bf16* __restrict__ qkv,
                                                 const float* __restrict__ qw,
                                                 const float* __restrict__ kw,
                                                 const int* __restrict__ pos,
                                                 bf16* __restrict__ qn,
                                                 bf16* __restrict__ kn) {
  const int t   = blockIdx.x;
  const int hr  = blockIdx.y;
  const int tid = threadIdx.x;
  const bool isq = hr < 16;
  const int col  = isq ? hr * 128 : 2048 + (hr - 16) * 128;

  float x = (float)qkv[(size_t)t * 4096 + col + tid];
  float ss = x * x;
#pragma unroll
  for (int o = 32; o >= 1; o >>= 1) ss += __shfl_xor(ss, o);
  __shared__ float part[2];
  __shared__ float sh[128];
  if ((tid & 63) == 0) part[tid >> 6] = ss;
  __syncthreads();
  float total = part[0] + part[1];
  float rms = rsqrtf(total * (1.0f / 128.0f) + 1e-6f);
  const float* w = isq ? qw : kw;
  float xn = x * rms * w[tid];
  sh[tid] = xn;
  __syncthreads();

  int d = tid & 63;
  float inv = exp2f((float)d * (-19.93156856932417f / 64.0f));
  float fr = (float)pos[t] * inv;
  float sn, cs;
  sincosf(fr, &sn, &cs);
  float out = (tid < 64) ? (sh[tid] * cs - sh[tid + 64] * sn)
                         : (sh[tid] * cs + sh[tid - 64] * sn);
  if (isq) qn[(size_t)t * 2048 + hr * 128 + tid] = (bf16)out;
  else     kn[(size_t)t * 1024 + (hr - 16) * 128 + tid] = (bf16)out;
}

// ---------------------------------------------------------------------------
// One-time V transpose — unchanged
// ---------------------------------------------------------------------------
__global__ __launch_bounds__(256) void transpose_v(const bf16* __restrict__ qkv,
                                                   bf16* __restrict__ vt) {
  __shared__ __align__(16) bf16 tile[128 * 72];
  const int t0 = blockIdx.x * 64, kvh = blockIdx.y;
  const int tid = threadIdx.x;
#pragma unroll
  for (int it = 0; it < 2; ++it) {
    int linear = it * 4096 + tid * 16;
    int r = linear >> 7, c = linear & 127;
    union { uint4 v; bf16 e[8]; } u0, u1;
    u0.v = *reinterpret_cast<const uint4*>(
        &qkv[(size_t)(t0 + r) * 4096 + 3072 + kvh * 128 + c]);
    u1.v = *reinterpret_cast<const uint4*>(
        &qkv[(size_t)(t0 + r) * 4096 + 3072 + kvh * 128 + c + 8]);
#pragma unroll
    for (int j = 0; j < 8; ++j) tile[(c + j) * 72 + r] = u0.e[j];
#pragma unroll
    for (int j = 0; j < 8; ++j) tile[(c + 8 + j) * 72 + r] = u1.e[j];
  }
  __syncthreads();
#pragma unroll
  for (int it = 0; it < 4; ++it) {
    int linear = it * 2048 + tid * 8;
    int d = linear >> 6, c = linear & 63;
    uint4 v = *reinterpret_cast<const uint4*>(&tile[d * 72 + c]);
    *reinterpret_cast<uint4*>(&vt[(size_t)(kvh * 128 + d) * 4096 + t0 + c]) = v;
  }
}

// ---------------------------------------------------------------------------
// Flash attention v5. grid (32, 16 heads), block 256, one head per block.
// Block bx handles q-tiles {bx, 63-bx} sequentially -> EXACTLY 65 k-tile
// units per block: perfect CU load balance with all 512 blocks resident.
// S^T = K.Q^T (16x16x32); P stays in registers and feeds O^T += V^T.P via
// chained v_mfma_f32_16x16x16_bf16 (S^T C-layout == A/B frag layout).
// Register prefetch of next K/V tile, incl. across the phase boundary.
// ---------------------------------------------------------------------------
__global__ __launch_bounds__(256) void attn(const bf16* __restrict__ q,
                                            const bf16* __restrict__ k,
                                            const bf16* __restrict__ vt,
                                            bf16* __restrict__ out) {
  __shared__ __align__(16) bf16 Ks[64 * 136];  // [kv row][dim]
  __shared__ __align__(16) bf16 Vs[128 * 72];  // [dim][kv row]

  const int head = blockIdx.y, kvh = head >> 1;
  const int bx = blockIdx.x;

  const int tid = threadIdx.x;
  const int wave = tid >> 6, lane = tid & 63;
  const int quad = lane >> 4, l16 = lane & 15;
  const float cExp = 0.08838834764831845f * 1.4426950408889634f; // scale*log2e
  const f32x4 zero = {0.f, 0.f, 0.f, 0.f};

  // ---- prefetch phase-0 tile 0 into registers ----
  uint4 pk[4], pv[4];
#pragma unroll
  for (int it = 0; it < 4; ++it) {
    int linear = it * 2048 + tid * 8;
    int r = linear >> 7, c = linear & 127;
    pk[it] = *reinterpret_cast<const uint4*>(&k[(size_t)r * 1024 + kvh * 128 + c]);
    int d = linear >> 6, c2 = linear & 63;
    pv[it] = *reinterpret_cast<const uint4*>(&vt[(size_t)(kvh * 128 + d) * 4096 + c2]);
  }

#pragma unroll
  for (int phase = 0; phase < 2; ++phase) {
    const int qt = phase == 0 ? bx : 63 - bx;
    const int q0 = qt * 64;
    const int kend = q0 + 64;
    const int qrow = q0 + wave * 16 + l16;

    // Q fragments: B[n=l16][k=s*32+quad*8+j]
    bf16x8 qf[4];
#pragma unroll
    for (int s = 0; s < 4; ++s)
      qf[s] = *reinterpret_cast<const bf16x8*>(
          &q[(size_t)qrow * 2048 + head * 128 + s * 32 + quad * 8]);

    f32x4 o_acc[8];  // O^T: d = dt*16+quad*4+r, q = l16
#pragma unroll
    for (int dt = 0; dt < 8; ++dt) o_acc[dt] = zero;
    float m_i = -3.0e38f, l_i = 0.f;

    for (int k0 = 0; k0 < kend; k0 += 64) {
      // ---- publish prefetched tile to LDS ----
#pragma unroll
      for (int it = 0; it < 4; ++it) {
        int linear = it * 2048 + tid * 8;
        int r = linear >> 7, c = linear & 127;
        *reinterpret_cast<uint4*>(&Ks[r * 136 + c]) = pk[it];
        int d = linear >> 6, c2 = linear & 63;
        *reinterpret_cast<uint4*>(&Vs[d * 72 + c2]) = pv[it];
      }
      __syncthreads();

      // ---- prefetch next tile (next k0, or phase-1 tile 0) ----
      int nk0 = -1;
      if (k0 + 64 < kend)     nk0 = k0 + 64;
      else if (phase == 0)    nk0 = 0;
      if (nk0 >= 0) {
#pragma unroll
        for (int it = 0; it < 4; ++it) {
          int linear = it * 2048 + tid * 8;
          int r = linear >> 7, c = linear & 127;
          pk[it] = *reinterpret_cast<const uint4*>(
              &k[(size_t)(nk0 + r) * 1024 + kvh * 128 + c]);
          int d = linear >> 6, c2 = linear & 63;
          pv[it] = *reinterpret_cast<const uint4*>(
              &vt[(size_t)(kvh * 128 + d) * 4096 + nk0 + c2]);
        }
      }

      // ---- S^T = K Q^T : rows t (4 tiles of 16), cols q (16) ----
      f32x4 s_acc[4];
#pragma unroll
      for (int mt = 0; mt < 4; ++mt) {
        bf16x8 kf[4];
#pragma unroll
        for (int ks = 0; ks < 4; ++ks)
          kf[ks] = *reinterpret_cast<const bf16x8*>(
              &Ks[(mt * 16 + l16) * 136 + ks * 32 + quad * 8]);
        f32x4 sa = zero;
#pragma unroll
        for (int ks = 0; ks < 4; ++ks) sa = mfma16(kf[ks], qf[ks], sa);
        s_acc[mt] = sa;
      }

      // ---- causal mask (diagonal tile only): t > q -> -inf ----
      if (k0 == q0) {
        int tq = wave * 16 + l16;
#pragma unroll
        for (int mt = 0; mt < 4; ++mt)
#pragma unroll
          for (int r = 0; r < 4; ++r) {
            int tk = mt * 16 + quad * 4 + r;
            if (tk > tq) s_acc[mt][r] = -3.0e38f;
          }
      }

      // ---- online softmax: q fixed per lane (l16); reduce regs + quads ----
      {
        float mx = -3.0e38f;
#pragma unroll
        for (int mt = 0; mt < 4; ++mt)
#pragma unroll
          for (int r = 0; r < 4; ++r) mx = fmaxf(mx, s_acc[mt][r]);
        mx = fmaxf(mx, __shfl_xor(mx, 16));
        mx = fmaxf(mx, __shfl_xor(mx, 32));
        float mn = fmaxf(m_i, mx);
        float al = exp2f((m_i - mn) * cExp);
        m_i = mn;
        float nmc = -mn * cExp;
        float rs = 0.f;
#pragma unroll
        for (int mt = 0; mt < 4; ++mt)
#pragma unroll
          for (int r = 0; r < 4; ++r) {
            float pe = exp2f(fmaf(s_acc[mt][r], cExp, nmc));
            s_acc[mt][r] = pe;
            rs += pe;
          }
        rs += __shfl_xor(rs, 16);
        rs += __shfl_xor(rs, 32);
        l_i = l_i * al + rs;
#pragma unroll
        for (int dt = 0; dt < 8; ++dt)
#pragma unroll
          for (int r = 0; r < 4; ++r) o_acc[dt][r] *= al;
      }

      // ---- pack P in-register: B[k=t=quad*4+j][n=q=l16] per mt ----
      bf16x4 pb[4];
#pragma unroll
      for (int mt = 0; mt < 4; ++mt) {
        bf16x4 t;
#pragma unroll
        for (int r = 0; r < 4; ++r) t[r] = (bf16)s_acc[mt][r];
        pb[mt] = t;
      }

      // ---- O^T += V^T P via chained 16x16x16 ----
#pragma unroll
      for (int dt = 0; dt < 8; ++dt) {
        bf16x4 va0 = *reinterpret_cast<const bf16x4*>(
            &Vs[(dt * 16 + l16) * 72 + 0 * 16 + quad * 4]);
        bf16x4 va1 = *reinterpret_cast<const bf16x4*>(
            &Vs[(dt * 16 + l16) * 72 + 1 * 16 + quad * 4]);
        bf16x4 va2 = *reinterpret_cast<const bf16x4*>(
            &Vs[(dt * 16 + l16) * 72 + 2 * 16 + quad * 4]);
        bf16x4 va3 = *reinterpret_cast<const bf16x4*>(
            &Vs[(dt * 16 + l16) * 72 + 3 * 16 + quad * 4]);
        mfma16x16_chain4(va0, va1, va2, va3, pb[0], pb[1], pb[2], pb[3],
                         o_acc[dt]);
      }
      __syncthreads();  // all waves done with Ks/Vs before next publish
    }

    // ---- epilogue: O = O^T/l, 4 contiguous d per reg-quad ----
    float rl = __builtin_amdgcn_rcpf(l_i);
#pragma unroll
    for (int dt = 0; dt < 8; ++dt) {
      bf16x4 ov;
#pragma unroll
      for (int r = 0; r < 4; ++r) ov[r] = (bf16)(o_acc[dt][r] * rl);
      *reinterpret_cast<bf16x4*>(
          &out[(size_t)qrow * 2048 + head * 128 + dt * 16 + quad * 4]) = ov;
    }
  }
}

// ---------------------------------------------------------------------------
extern "C" void kernel_launch(void* const* d_in, const int* in_sizes, int n_in,
                              void* d_out, int out_size, void* d_ws, size_t ws_size,
                              hipStream_t stream) {
  const float* hidden = (const float*)d_in[0];
  const float* qkv_w  = (const float*)d_in[1];
  const float* qnw    = (const float*)d_in[2];
  const float* knw    = (const float*)d_in[3];
  const float* o_w    = (const float*)d_in[4];
  const int*   pos    = (const int*)d_in[5];

  bf16* qkv = (bf16*)d_ws;                       // 4096*4096
  bf16* qn  = qkv + (size_t)4096 * 4096;         // 4096*2048
  bf16* kn  = qn  + (size_t)4096 * 2048;         // 4096*1024
  bf16* vt  = kn  + (size_t)4096 * 1024;         // 1024*4096
  bf16* ao  = vt  + (size_t)1024 * 4096;         // 4096*2048
  bf16* hb  = ao;   // bf16 hidden, dead before attn writes ao
  bf16* wq  = kn;   // bf16 qkv_w, dead before norm_rope/transpose write kn/vt
  bf16* wo  = qn;   // bf16 o_w, cast after attn (qn dead)
  float* out = (float*)d_out;

  cast_bf16<<<4096, 256, 0, stream>>>(hidden, hb);
  cast_bf16<<<4096, 256, 0, stream>>>(qkv_w, wq);
  gemm_bt<<<dim3(32, 32), 256, 0, stream>>>(hb, wq, qkv, 4096, 4096, 2048);
  norm_rope<<<dim3(4096, 24), 128, 0, stream>>>(qkv, qnw, knw, pos, qn, kn);
  transpose_v<<<dim3(64, 8), 256, 0, stream>>>(qkv, vt);
  attn<<<dim3(32, 16), 256, 0, stream>>>(qn, kn, vt, ao);
  cast_bf16<<<2048, 256, 0, stream>>>(o_w, wo);
  gemm_bt<<<dim3(16, 32), 256, 0, stream>>>(ao, wo, out, 4096, 2048, 2048);
}

// Round 7
// 697.317 us; speedup vs baseline: 1.3136x; 1.0024x over previous
//
#include <hip/hip_runtime.h>
#include <hip/hip_bf16.h>
#include <math.h>

// ---------------------------------------------------------------------------
// Qwen3 attention block: T=4096, HIDDEN=2048, 16 Q heads, 8 KV heads,
// HEAD_DIM=128, rope theta 1e6, rms eps 1e-6, causal.
// fp32 in/out; bf16 internally for MFMA with fp32 accumulation.
//
// ws layout (84 MB, regions reused across phases):
//   qkv  bf16 [4096][4096]  @ 0
//   qn   bf16 [4096][2048]  (also wo after attn)
//   kn   bf16 [4096][1024]  (kn+vt region doubles as wq pre-gemm1)
//   vt   bf16 [1024][4096]
//   ao   bf16 [4096][2048]  (doubles as hb pre-attn)
// ---------------------------------------------------------------------------

typedef __bf16 bf16;
typedef __bf16 bf16x4 __attribute__((ext_vector_type(4)));
typedef __bf16 bf16x8 __attribute__((ext_vector_type(8)));
typedef float  f32x4  __attribute__((ext_vector_type(4)));

__device__ __forceinline__ f32x4 mfma16(bf16x8 a, bf16x8 b, f32x4 c) {
  return __builtin_amdgcn_mfma_f32_16x16x32_bf16(a, b, c, 0, 0, 0);
}

// 4 chained 16x16x16 bf16 MFMAs accumulating into one C/D quad.
// A/B frag [m|n = l16][k = quad*4 + j] == S^T C-layout, so P feeds PV directly
// from registers. Single leading s_nop 2 covers the VALU-write -> MFMA-read
// hazard (same-acc MFMA->MFMA chains are HW-interlocked).
__device__ __forceinline__ void mfma16x16_chain4(const bf16x4& a0, const bf16x4& a1,
                                                 const bf16x4& a2, const bf16x4& a3,
                                                 const bf16x4& b0, const bf16x4& b1,
                                                 const bf16x4& b2, const bf16x4& b3,
                                                 f32x4& c) {
  asm volatile(
      "s_nop 2\n\t"
      "v_mfma_f32_16x16x16_bf16 %0, %1, %5, %0\n\t"
      "v_mfma_f32_16x16x16_bf16 %0, %2, %6, %0\n\t"
      "v_mfma_f32_16x16x16_bf16 %0, %3, %7, %0\n\t"
      "v_mfma_f32_16x16x16_bf16 %0, %4, %8, %0"
      : "+v"(c)
      : "v"(a0), "v"(a1), "v"(a2), "v"(a3),
        "v"(b0), "v"(b1), "v"(b2), "v"(b3));
}

__device__ __forceinline__ void load8_to_lds(const float* src, bf16* dst) {
  float4 a = *reinterpret_cast<const float4*>(src);
  float4 b = *reinterpret_cast<const float4*>(src + 4);
  bf16x8 v = {(bf16)a.x, (bf16)a.y, (bf16)a.z, (bf16)a.w,
              (bf16)b.x, (bf16)b.y, (bf16)b.z, (bf16)b.w};
  *reinterpret_cast<bf16x8*>(dst) = v;
}
__device__ __forceinline__ void load8_to_lds(const bf16* src, bf16* dst) {
  *reinterpret_cast<uint4*>(dst) = *reinterpret_cast<const uint4*>(src);
}
__device__ __forceinline__ void store_c(float* p, float v) { *p = v; }
__device__ __forceinline__ void store_c(bf16* p, float v) { *p = (bf16)v; }

// ---------------------------------------------------------------------------
// fp32 -> bf16 cast, 8 elems/thread
// ---------------------------------------------------------------------------
__global__ __launch_bounds__(256) void cast_bf16(const float* __restrict__ s,
                                                 bf16* __restrict__ d) {
  int i = blockIdx.x * 256 + threadIdx.x;
  float4 a = reinterpret_cast<const float4*>(s)[i * 2];
  float4 b = reinterpret_cast<const float4*>(s)[i * 2 + 1];
  bf16x8 v = {(bf16)a.x, (bf16)a.y, (bf16)a.z, (bf16)a.w,
              (bf16)b.x, (bf16)b.y, (bf16)b.z, (bf16)b.w};
  reinterpret_cast<bf16x8*>(d)[i] = v;
}

// ---------------------------------------------------------------------------
// C[M][N] = A[M][K] @ B[N][K]^T   (fp32 accumulate) — unchanged
// ---------------------------------------------------------------------------
template <typename TA, typename TB, typename TC>
__global__ __launch_bounds__(256) void gemm_bt(const TA* __restrict__ A,
                                               const TB* __restrict__ B,
                                               TC* __restrict__ C,
                                               int M, int N, int K) {
  __shared__ __align__(16) bf16 As[128 * 40];
  __shared__ __align__(16) bf16 Bs[128 * 40];

  const int tid  = threadIdx.x;
  const int wave = tid >> 6, lane = tid & 63;
  const int quad = lane >> 4, l16 = lane & 15;
  const int wm = (wave >> 1) * 64, wn = (wave & 1) * 64;
  const int n0 = blockIdx.x * 128, m0 = blockIdx.y * 128;

  const f32x4 zero = {0.f, 0.f, 0.f, 0.f};
  f32x4 acc[4][4];
#pragma unroll
  for (int i = 0; i < 4; ++i)
#pragma unroll
    for (int j = 0; j < 4; ++j) acc[i][j] = zero;

  for (int k0 = 0; k0 < K; k0 += 32) {
#pragma unroll
    for (int it = 0; it < 2; ++it) {
      int linear = it * 2048 + tid * 8;
      int r = linear >> 5, c = linear & 31;
      load8_to_lds(&A[(size_t)(m0 + r) * K + k0 + c], &As[r * 40 + c]);
      load8_to_lds(&B[(size_t)(n0 + r) * K + k0 + c], &Bs[r * 40 + c]);
    }
    __syncthreads();

    bf16x8 af[4], bfr[4];
#pragma unroll
    for (int i = 0; i < 4; ++i)
      af[i] = *reinterpret_cast<const bf16x8*>(&As[(wm + i * 16 + l16) * 40 + quad * 8]);
#pragma unroll
    for (int j = 0; j < 4; ++j)
      bfr[j] = *reinterpret_cast<const bf16x8*>(&Bs[(wn + j * 16 + l16) * 40 + quad * 8]);
#pragma unroll
    for (int i = 0; i < 4; ++i)
#pragma unroll
      for (int j = 0; j < 4; ++j)
        acc[i][j] = mfma16(af[i], bfr[j], acc[i][j]);
    __syncthreads();
  }

#pragma unroll
  for (int i = 0; i < 4; ++i)
#pragma unroll
    for (int j = 0; j < 4; ++j)
#pragma unroll
      for (int r = 0; r < 4; ++r) {
        int row = m0 + wm + i * 16 + quad * 4 + r;
        int col = n0 + wn + j * 16 + l16;
        store_c(&C[(size_t)row * N + col], acc[i][j][r]);
      }
}

// ---------------------------------------------------------------------------
// Per-(token, head) RMS norm + rope — unchanged
// ---------------------------------------------------------------------------
__global__ __launch_bounds__(128) void norm_rope(const bf16* __restrict__ qkv,
                                                 const float* __restrict__ qw,
                                                 const float* __restrict__ kw,
                                                 const int* __restrict__ pos,
                                                 bf16* __restrict__ qn,
                                                 bf16* __restrict__ kn) {
  const int t   = blockIdx.x;
  const int hr  = blockIdx.y;
  const int tid = threadIdx.x;
  const bool isq = hr < 16;
  const int col  = isq ? hr * 128 : 2048 + (hr - 16) * 128;

  float x = (float)qkv[(size_t)t * 4096 + col + tid];
  float ss = x * x;
#pragma unroll
  for (int o = 32; o >= 1; o >>= 1) ss += __shfl_xor(ss, o);
  __shared__ float part[2];
  __shared__ float sh[128];
  if ((tid & 63) == 0) part[tid >> 6] = ss;
  __syncthreads();
  float total = part[0] + part[1];
  float rms = rsqrtf(total * (1.0f / 128.0f) + 1e-6f);
  const float* w = isq ? qw : kw;
  float xn = x * rms * w[tid];
  sh[tid] = xn;
  __syncthreads();

  int d = tid & 63;
  float inv = exp2f((float)d * (-19.93156856932417f / 64.0f));
  float fr = (float)pos[t] * inv;
  float sn, cs;
  sincosf(fr, &sn, &cs);
  float out = (tid < 64) ? (sh[tid] * cs - sh[tid + 64] * sn)
                         : (sh[tid] * cs + sh[tid - 64] * sn);
  if (isq) qn[(size_t)t * 2048 + hr * 128 + tid] = (bf16)out;
  else     kn[(size_t)t * 1024 + (hr - 16) * 128 + tid] = (bf16)out;
}

// ---------------------------------------------------------------------------
// One-time V transpose — unchanged
// ---------------------------------------------------------------------------
__global__ __launch_bounds__(256) void transpose_v(const bf16* __restrict__ qkv,
                                                   bf16* __restrict__ vt) {
  __shared__ __align__(16) bf16 tile[128 * 72];
  const int t0 = blockIdx.x * 64, kvh = blockIdx.y;
  const int tid = threadIdx.x;
#pragma unroll
  for (int it = 0; it < 2; ++it) {
    int linear = it * 4096 + tid * 16;
    int r = linear >> 7, c = linear & 127;
    union { uint4 v; bf16 e[8]; } u0, u1;
    u0.v = *reinterpret_cast<const uint4*>(
        &qkv[(size_t)(t0 + r) * 4096 + 3072 + kvh * 128 + c]);
    u1.v = *reinterpret_cast<const uint4*>(
        &qkv[(size_t)(t0 + r) * 4096 + 3072 + kvh * 128 + c + 8]);
#pragma unroll
    for (int j = 0; j < 8; ++j) tile[(c + j) * 72 + r] = u0.e[j];
#pragma unroll
    for (int j = 0; j < 8; ++j) tile[(c + 8 + j) * 72 + r] = u1.e[j];
  }
  __syncthreads();
#pragma unroll
  for (int it = 0; it < 4; ++it) {
    int linear = it * 2048 + tid * 8;
    int d = linear >> 6, c = linear & 63;
    uint4 v = *reinterpret_cast<const uint4*>(&tile[d * 72 + c]);
    *reinterpret_cast<uint4*>(&vt[(size_t)(kvh * 128 + d) * 4096 + t0 + c]) = v;
  }
}

// ---------------------------------------------------------------------------
// Flash attention v6. grid (32, 16 heads), block 256, one head per block.
// Block bx handles q-tiles {bx, 63-bx} sequentially -> exactly 65 k-tile
// units per block: perfect CU load balance with all 512 blocks resident.
// __launch_bounds__(256, 2): 256-VGPR budget -- live state is ~150 VGPRs
// (K/V prefetch 32 + o_acc 32 + qf 16 + s/pb 24 + addr); the R6 default
// targeted 6 waves/SIMD (84 VGPRs) and spilled 725 MB/launch to scratch.
// Resident grid needs only 2 blocks/CU = 2 waves/SIMD, so cap there.
// ---------------------------------------------------------------------------
__global__ __launch_bounds__(256, 2) void attn(const bf16* __restrict__ q,
                                               const bf16* __restrict__ k,
                                               const bf16* __restrict__ vt,
                                               bf16* __restrict__ out) {
  __shared__ __align__(16) bf16 Ks[64 * 136];  // [kv row][dim]
  __shared__ __align__(16) bf16 Vs[128 * 72];  // [dim][kv row]

  const int head = blockIdx.y, kvh = head >> 1;
  const int bx = blockIdx.x;

  const int tid = threadIdx.x;
  const int wave = tid >> 6, lane = tid & 63;
  const int quad = lane >> 4, l16 = lane & 15;
  const float cExp = 0.08838834764831845f * 1.4426950408889634f; // scale*log2e
  const f32x4 zero = {0.f, 0.f, 0.f, 0.f};

  // ---- prefetch phase-0 tile 0 into registers ----
  uint4 pk[4], pv[4];
#pragma unroll
  for (int it = 0; it < 4; ++it) {
    int linear = it * 2048 + tid * 8;
    int r = linear >> 7, c = linear & 127;
    pk[it] = *reinterpret_cast<const uint4*>(&k[(size_t)r * 1024 + kvh * 128 + c]);
    int d = linear >> 6, c2 = linear & 63;
    pv[it] = *reinterpret_cast<const uint4*>(&vt[(size_t)(kvh * 128 + d) * 4096 + c2]);
  }

#pragma unroll
  for (int phase = 0; phase < 2; ++phase) {
    const int qt = phase == 0 ? bx : 63 - bx;
    const int q0 = qt * 64;
    const int kend = q0 + 64;
    const int qrow = q0 + wave * 16 + l16;

    // Q fragments: B[n=l16][k=s*32+quad*8+j]
    bf16x8 qf[4];
#pragma unroll
    for (int s = 0; s < 4; ++s)
      qf[s] = *reinterpret_cast<const bf16x8*>(
          &q[(size_t)qrow * 2048 + head * 128 + s * 32 + quad * 8]);

    f32x4 o_acc[8];  // O^T: d = dt*16+quad*4+r, q = l16
#pragma unroll
    for (int dt = 0; dt < 8; ++dt) o_acc[dt] = zero;
    float m_i = -3.0e38f, l_i = 0.f;

    for (int k0 = 0; k0 < kend; k0 += 64) {
      // ---- publish prefetched tile to LDS ----
#pragma unroll
      for (int it = 0; it < 4; ++it) {
        int linear = it * 2048 + tid * 8;
        int r = linear >> 7, c = linear & 127;
        *reinterpret_cast<uint4*>(&Ks[r * 136 + c]) = pk[it];
        int d = linear >> 6, c2 = linear & 63;
        *reinterpret_cast<uint4*>(&Vs[d * 72 + c2]) = pv[it];
      }
      __syncthreads();

      // ---- prefetch next tile (next k0, or phase-1 tile 0) ----
      int nk0 = -1;
      if (k0 + 64 < kend)     nk0 = k0 + 64;
      else if (phase == 0)    nk0 = 0;
      if (nk0 >= 0) {
#pragma unroll
        for (int it = 0; it < 4; ++it) {
          int linear = it * 2048 + tid * 8;
          int r = linear >> 7, c = linear & 127;
          pk[it] = *reinterpret_cast<const uint4*>(
              &k[(size_t)(nk0 + r) * 1024 + kvh * 128 + c]);
          int d = linear >> 6, c2 = linear & 63;
          pv[it] = *reinterpret_cast<const uint4*>(
              &vt[(size_t)(kvh * 128 + d) * 4096 + nk0 + c2]);
        }
      }

      // ---- S^T = K Q^T : rows t (4 tiles of 16), cols q (16) ----
      f32x4 s_acc[4];
#pragma unroll
      for (int mt = 0; mt < 4; ++mt) {
        bf16x8 kf[4];
#pragma unroll
        for (int ks = 0; ks < 4; ++ks)
          kf[ks] = *reinterpret_cast<const bf16x8*>(
              &Ks[(mt * 16 + l16) * 136 + ks * 32 + quad * 8]);
        f32x4 sa = zero;
#pragma unroll
        for (int ks = 0; ks < 4; ++ks) sa = mfma16(kf[ks], qf[ks], sa);
        s_acc[mt] = sa;
      }

      // ---- causal mask (diagonal tile only): t > q -> -inf ----
      if (k0 == q0) {
        int tq = wave * 16 + l16;
#pragma unroll
        for (int mt = 0; mt < 4; ++mt)
#pragma unroll
          for (int r = 0; r < 4; ++r) {
            int tk = mt * 16 + quad * 4 + r;
            if (tk > tq) s_acc[mt][r] = -3.0e38f;
          }
      }

      // ---- online softmax: q fixed per lane (l16); reduce regs + quads ----
      {
        float mx = -3.0e38f;
#pragma unroll
        for (int mt = 0; mt < 4; ++mt)
#pragma unroll
          for (int r = 0; r < 4; ++r) mx = fmaxf(mx, s_acc[mt][r]);
        mx = fmaxf(mx, __shfl_xor(mx, 16));
        mx = fmaxf(mx, __shfl_xor(mx, 32));
        float mn = fmaxf(m_i, mx);
        float al = exp2f((m_i - mn) * cExp);
        m_i = mn;
        float nmc = -mn * cExp;
        float rs = 0.f;
#pragma unroll
        for (int mt = 0; mt < 4; ++mt)
#pragma unroll
          for (int r = 0; r < 4; ++r) {
            float pe = exp2f(fmaf(s_acc[mt][r], cExp, nmc));
            s_acc[mt][r] = pe;
            rs += pe;
          }
        rs += __shfl_xor(rs, 16);
        rs += __shfl_xor(rs, 32);
        l_i = l_i * al + rs;
#pragma unroll
        for (int dt = 0; dt < 8; ++dt)
#pragma unroll
          for (int r = 0; r < 4; ++r) o_acc[dt][r] *= al;
      }

      // ---- pack P in-register: B[k=t=quad*4+j][n=q=l16] per mt ----
      bf16x4 pb[4];
#pragma unroll
      for (int mt = 0; mt < 4; ++mt) {
        bf16x4 t;
#pragma unroll
        for (int r = 0; r < 4; ++r) t[r] = (bf16)s_acc[mt][r];
        pb[mt] = t;
      }

      // ---- O^T += V^T P via chained 16x16x16 ----
#pragma unroll
      for (int dt = 0; dt < 8; ++dt) {
        bf16x4 va0 = *reinterpret_cast<const bf16x4*>(
            &Vs[(dt * 16 + l16) * 72 + 0 * 16 + quad * 4]);
        bf16x4 va1 = *reinterpret_cast<const bf16x4*>(
            &Vs[(dt * 16 + l16) * 72 + 1 * 16 + quad * 4]);
        bf16x4 va2 = *reinterpret_cast<const bf16x4*>(
            &Vs[(dt * 16 + l16) * 72 + 2 * 16 + quad * 4]);
        bf16x4 va3 = *reinterpret_cast<const bf16x4*>(
            &Vs[(dt * 16 + l16) * 72 + 3 * 16 + quad * 4]);
        mfma16x16_chain4(va0, va1, va2, va3, pb[0], pb[1], pb[2], pb[3],
                         o_acc[dt]);
      }
      __syncthreads();  // all waves done with Ks/Vs before next publish
    }

    // ---- epilogue: O = O^T/l, 4 contiguous d per reg-quad ----
    float rl = __builtin_amdgcn_rcpf(l_i);
#pragma unroll
    for (int dt = 0; dt < 8; ++dt) {
      bf16x4 ov;
#pragma unroll
      for (int r = 0; r < 4; ++r) ov[r] = (bf16)(o_acc[dt][r] * rl);
      *reinterpret_cast<bf16x4*>(
          &out[(size_t)qrow * 2048 + head * 128 + dt * 16 + quad * 4]) = ov;
    }
  }
}

// ---------------------------------------------------------------------------
extern "C" void kernel_launch(void* const* d_in, const int* in_sizes, int n_in,
                              void* d_out, int out_size, void* d_ws, size_t ws_size,
                              hipStream_t stream) {
  const float* hidden = (const float*)d_in[0];
  const float* qkv_w  = (const float*)d_in[1];
  const float* qnw    = (const float*)d_in[2];
  const float* knw    = (const float*)d_in[3];
  const float* o_w    = (const float*)d_in[4];
  const int*   pos    = (const int*)d_in[5];

  bf16* qkv = (bf16*)d_ws;                       // 4096*4096
  bf16* qn  = qkv + (size_t)4096 * 4096;         // 4096*2048
  bf16* kn  = qn  + (size_t)4096 * 2048;         // 4096*1024
  bf16* vt  = kn  + (size_t)4096 * 1024;         // 1024*4096
  bf16* ao  = vt  + (size_t)1024 * 4096;         // 4096*2048
  bf16* hb  = ao;   // bf16 hidden, dead before attn writes ao
  bf16* wq  = kn;   // bf16 qkv_w, dead before norm_rope/transpose write kn/vt
  bf16* wo  = qn;   // bf16 o_w, cast after attn (qn dead)
  float* out = (float*)d_out;

  cast_bf16<<<4096, 256, 0, stream>>>(hidden, hb);
  cast_bf16<<<4096, 256, 0, stream>>>(qkv_w, wq);
  gemm_bt<<<dim3(32, 32), 256, 0, stream>>>(hb, wq, qkv, 4096, 4096, 2048);
  norm_rope<<<dim3(4096, 24), 128, 0, stream>>>(qkv, qnw, knw, pos, qn, kn);
  transpose_v<<<dim3(64, 8), 256, 0, stream>>>(qkv, vt);
  attn<<<dim3(32, 16), 256, 0, stream>>>(qn, kn, vt, ao);
  cast_bf16<<<2048, 256, 0, stream>>>(o_w, wo);
  gemm_bt<<<dim3(16, 32), 256, 0, stream>>>(ao, wo, out, 4096, 2048, 2048);
}